// Round 2
// baseline (1629.868 us; speedup 1.0000x reference)
//
#include <hip/hip_runtime.h>
#include <math.h>

#define NPER  4096
#define NTOT  16384
#define EPER  49152
#define ETOT  196608
#define FD    128
#define F3    384
#define KR    20
#define PI_F  3.14159265358979f

typedef unsigned short u16;
typedef __attribute__((ext_vector_type(8))) short s16x8;
typedef __attribute__((ext_vector_type(4))) float f32x4;

__device__ __forceinline__ float silu_f(float x){ return x / (1.0f + __expf(-x)); }
__device__ __forceinline__ u16 f2b(float x){
    unsigned u = __float_as_uint(x);
    u = u + 0x7FFFu + ((u >> 16) & 1u);
    return (u16)(u >> 16);
}
__device__ __forceinline__ float b2f(u16 h){ return __uint_as_float(((unsigned)h) << 16); }

// ---------------- edge precompute ----------------
__global__ __launch_bounds__(256) void edge_kernel(
    const float* __restrict__ xyz, const float* __restrict__ cell,
    const int* __restrict__ aedges, const float* __restrict__ edisp,
    int* __restrict__ sendb, int* __restrict__ recvb,
    float* __restrict__ esb, float4* __restrict__ edata,
    int* __restrict__ counts)
{
    int e = blockIdx.x * blockDim.x + threadIdx.x;
    if (e >= ETOT) return;
    int b = e / EPER;
    int s = aedges[(size_t)e*2+0] + b*NPER;
    int r = aedges[(size_t)e*2+1] + b*NPER;
    const float* cb = cell + b*9;
    float c0 = edisp[(size_t)e*3+0], c1 = edisp[(size_t)e*3+1], c2 = edisp[(size_t)e*3+2];
    float diff[3];
    #pragma unroll
    for (int d=0; d<3; ++d) {
        float disp = c0*cb[d] + c1*cb[3+d] + c2*cb[6+d];
        diff[d] = xyz[(size_t)r*3+d] - (xyz[(size_t)s*3+d] + disp);
    }
    float dist = sqrtf(diff[0]*diff[0]+diff[1]*diff[1]+diff[2]*diff[2]);
    float cut = (dist < 5.0f) ? 0.5f*(cosf(PI_F*dist*0.2f)+1.0f) : 0.0f;
    float invg = 1.0f/fmaxf(dist,1e-12f);
    edata[e] = make_float4(diff[0]*invg, diff[1]*invg, diff[2]*invg, cut);
    float invd = 1.0f/dist;
    float ang = dist*(PI_F*0.2f);
    #pragma unroll
    for (int k=0;k<KR;++k) esb[(size_t)e*KR+k] = sinf(ang*(float)(k+1))*invd;
    sendb[e]=s; recvb[e]=r;
    atomicAdd(&counts[r],1);
}

// ---------------- exclusive scan counts -> row_off ----------------
__global__ __launch_bounds__(1024) void scan_kernel(const int* __restrict__ counts,
                                                    int* __restrict__ row_off)
{
    __shared__ int sdata[1024];
    int t = threadIdx.x;
    int base = t * 16;
    int local[16];
    int s = 0;
    #pragma unroll
    for (int i=0;i<16;++i){ local[i]=s; s += counts[base+i]; }
    sdata[t] = s;
    __syncthreads();
    for (int off=1; off<1024; off<<=1) {
        int val = (t>=off) ? sdata[t-off] : 0;
        __syncthreads();
        sdata[t] += val;
        __syncthreads();
    }
    int chunk_off = (t==0) ? 0 : sdata[t-1];
    #pragma unroll
    for (int i=0;i<16;++i) row_off[base+i] = chunk_off + local[i];
    if (t==1023) row_off[NTOT] = sdata[1023];
}

// ---------------- CSR fill ----------------
__global__ __launch_bounds__(256) void fill_kernel(const int* __restrict__ recvb,
    const int* __restrict__ row_off, int* __restrict__ cursor, int* __restrict__ perm)
{
    int e = blockIdx.x * blockDim.x + threadIdx.x;
    if (e >= ETOT) return;
    int r = recvb[e];
    int slot = atomicAdd(&cursor[r], 1);
    perm[row_off[r] + slot] = e;
}

// ---------------- weight fp32 -> bf16 conversion (one kernel, fixed offsets) --------
__global__ __launch_bounds__(256) void wconv_kernel(
    const float* __restrict__ w0, const float* __restrict__ w1,
    const float* __restrict__ w2, const float* __restrict__ w3,
    const float* __restrict__ w4, const float* __restrict__ w5,
    const float* __restrict__ w6, const float* __restrict__ w7,
    u16* __restrict__ dst)
{
    int t = blockIdx.x*256 + threadIdx.x;
    if (t >= 589824) return;
    const float* src; int off;
    if      (t < 32768)  { src=w0; off=t; }
    else if (t < 49152)  { src=w1; off=t-32768; }
    else if (t < 98304)  { src=w2; off=t-49152; }
    else if (t < 245760) { src=w3; off=t-98304; }
    else if (t < 294912) { src=w4; off=t-245760; }
    else if (t < 344064) { src=w5; off=t-294912; }
    else if (t < 442368) { src=w6; off=t-344064; }
    else                 { src=w7; off=t-442368; }
    dst[t] = f2b(src[off]);
}

// ---------------- h = [atom_emb[nodes], V*potW + potb] -> bf16 ----------------
__global__ __launch_bounds__(256) void hbuild_kernel(const int* __restrict__ nodes,
    const float* __restrict__ atom_emb, const float* __restrict__ V_flat,
    const float* __restrict__ pot_W, const float* __restrict__ pot_b,
    u16* __restrict__ h)
{
    int t = blockIdx.x * blockDim.x + threadIdx.x;   // NTOT*256
    int n = t >> 8, k = t & 255;
    float val;
    if (k < FD) val = atom_emb[(size_t)nodes[n]*FD + k];
    else { int f = k - FD; val = V_flat[n]*pot_W[f] + pot_b[f]; }
    h[t] = f2b(val);
}

// ---------------- v0 = E_flat[:,c] * vec_w[f] (fp32 + bf16) ----------------
__global__ __launch_bounds__(256) void v0_kernel(const float* __restrict__ E_flat,
    const float* __restrict__ vec_w, float* __restrict__ v0, u16* __restrict__ v0b)
{
    int t = blockIdx.x * blockDim.x + threadIdx.x;   // NTOT*384
    int n = t / F3, r = t - n*F3;
    int c = r >> 7, f = r & 127;
    float val = E_flat[(size_t)n*3 + c] * vec_w[f];
    v0[t] = val; v0b[t] = f2b(val);
}

// ---------------- bf16 MFMA GEMM: C[MxN] = act(A[MxK] @ W[NxK]^T + b) ----------------
// 256 threads = 4 waves; wave w computes rows [by*64+w*16, +16) x cols [bx*64, +64)
// A frag: lane=q*16+m holds A[m][q*8 .. q*8+7]; B frag same on W rows (= B^T);
// C/D: col=lane&15, row=q*4+reg.
template<int ACT>
__global__ __launch_bounds__(256) void bgemm_kernel(
    const u16* __restrict__ A, int lda,
    const u16* __restrict__ W, int Kdim,
    const float* __restrict__ bias,
    float* __restrict__ C, int ldc,
    u16* __restrict__ Cb, int ldcb)
{
    const int tid  = threadIdx.x;
    const int wave = tid >> 6, lane = tid & 63;
    const int q = lane >> 4, im = lane & 15;
    const int row0 = blockIdx.y*64 + wave*16;
    const int col0 = blockIdx.x*64;
    f32x4 acc[4];
    #pragma unroll
    for (int n=0;n<4;++n) acc[n] = (f32x4){0.f,0.f,0.f,0.f};
    const u16* Ap = A + (size_t)(row0+im)*lda + q*8;
    const u16* Wp = W + (size_t)(col0+im)*Kdim + q*8;
    for (int k0 = 0; k0 < Kdim; k0 += 32) {
        s16x8 af = *(const s16x8*)(Ap + k0);
        #pragma unroll
        for (int n=0;n<4;++n) {
            s16x8 bf = *(const s16x8*)(Wp + (size_t)n*16*Kdim + k0);
            acc[n] = __builtin_amdgcn_mfma_f32_16x16x32_bf16(af, bf, acc[n], 0, 0, 0);
        }
    }
    #pragma unroll
    for (int n=0;n<4;++n) {
        int col = col0 + n*16 + im;
        float bv = bias ? bias[col] : 0.f;
        #pragma unroll
        for (int r=0;r<4;++r) {
            int row = row0 + q*4 + r;
            float v = acc[n][r] + bv;
            if (ACT) v = silu_f(v);
            if (C)  C[(size_t)row*ldc + col] = v;
            if (Cb) Cb[(size_t)row*ldcb + col] = f2b(v);
        }
    }
}

// ---------------- fused filter + gather aggregation ----------------
// 256 threads: f = tid&127, sub = tid>>7 -> node 2i+sub. Filter weights in REGISTERS.
__global__ __launch_bounds__(256) void agg_kernel(
    const float* __restrict__ s_prev_f, int s_ldaf,
    const float* __restrict__ v_prev_f, int v_nstrf,
    const u16* __restrict__ s_prev_b,
    const u16* __restrict__ v_prev_b,
    const u16* __restrict__ so_b,
    const float* __restrict__ esb,
    const float4* __restrict__ edata,
    const int* __restrict__ row_off, const int* __restrict__ perm,
    const int* __restrict__ sendb,
    const float* __restrict__ fW, const float* __restrict__ fb,
    float* __restrict__ s_mid, float* __restrict__ v_mid,
    u16* __restrict__ v_mid_b)
{
    const int f   = threadIdx.x & 127;
    const int sub = threadIdx.x >> 7;
    float w0[KR], w1[KR], w2[KR];
    {
        const float4* p0 = (const float4*)(fW + (size_t)f*KR);
        const float4* p1 = (const float4*)(fW + (size_t)(FD+f)*KR);
        const float4* p2 = (const float4*)(fW + (size_t)(2*FD+f)*KR);
        #pragma unroll
        for (int i=0;i<5;++i){
            float4 a=p0[i], b=p1[i], c=p2[i];
            w0[4*i]=a.x; w0[4*i+1]=a.y; w0[4*i+2]=a.z; w0[4*i+3]=a.w;
            w1[4*i]=b.x; w1[4*i+1]=b.y; w1[4*i+2]=b.z; w1[4*i+3]=b.w;
            w2[4*i]=c.x; w2[4*i+1]=c.y; w2[4*i+2]=c.z; w2[4*i+3]=c.w;
        }
    }
    const float b0 = fb[f], b1 = fb[FD+f], b2 = fb[2*FD+f];

    for (int n = blockIdx.x*2 + sub; n < NTOT; n += gridDim.x*2) {
        int beg = row_off[n], end = row_off[n+1];
        float acc_s=0.f, av0=0.f, av1=0.f, av2=0.f;
        for (int idx = beg; idx < end; ++idx) {
            int e  = perm[idx];
            int sd = sendb[e];
            float4 ed = edata[e];
            const float4* ep = (const float4*)(esb + (size_t)e*KR);
            float d0=0.f, d1=0.f, d2=0.f;
            #pragma unroll
            for (int i=0;i<5;++i){
                float4 es4 = ep[i];
                d0 += es4.x*w0[4*i] + es4.y*w0[4*i+1] + es4.z*w0[4*i+2] + es4.w*w0[4*i+3];
                d1 += es4.x*w1[4*i] + es4.y*w1[4*i+1] + es4.z*w1[4*i+2] + es4.w*w1[4*i+3];
                d2 += es4.x*w2[4*i] + es4.y*w2[4*i+1] + es4.z*w2[4*i+2] + es4.w*w2[4*i+3];
            }
            float g_sv = (d0+b0)*ed.w, g_ev = (d1+b1)*ed.w, g_ns = (d2+b2)*ed.w;
            size_t sb = (size_t)sd*F3;
            float fo_sv = g_sv * b2f(so_b[sb+f]);
            float fo_ev = g_ev * b2f(so_b[sb+FD+f]);
            float fo_ns = g_ns * b2f(so_b[sb+2*FD+f]);
            acc_s += b2f(s_prev_b[(size_t)sd*FD+f]) * fo_ns;
            av0 += b2f(v_prev_b[sb+f])      * fo_sv + fo_ev*ed.x;
            av1 += b2f(v_prev_b[sb+FD+f])   * fo_sv + fo_ev*ed.y;
            av2 += b2f(v_prev_b[sb+2*FD+f]) * fo_sv + fo_ev*ed.z;
        }
        s_mid[(size_t)n*FD+f] = s_prev_f[(size_t)n*s_ldaf+f] + acc_s;
        const float* vp = v_prev_f + (size_t)n*v_nstrf;
        float o0 = vp[f]+av0, o1 = vp[FD+f]+av1, o2 = vp[2*FD+f]+av2;
        size_t vo = (size_t)n*F3;
        v_mid[vo+f]=o0;       v_mid[vo+FD+f]=o1;       v_mid[vo+2*FD+f]=o2;
        v_mid_b[vo+f]=f2b(o0); v_mid_b[vo+FD+f]=f2b(o1); v_mid_b[vo+2*FD+f]=f2b(o2);
    }
}

// ---------------- Vn, dot(Uv,Vv); m = [s_mid, Vn] (bf16) ----------------
__global__ __launch_bounds__(256) void vndot_kernel(
    const float* __restrict__ Uv, const float* __restrict__ Vv,
    const float* __restrict__ s_mid,
    u16* __restrict__ mbuf, float* __restrict__ dotb)
{
    int t = blockIdx.x * blockDim.x + threadIdx.x;   // NTOT*128
    int n = t >> 7, f = t & 127;
    size_t b0 = (size_t)n*3*FD + f;
    float u0 = Uv[b0], u1 = Uv[b0+FD], u2 = Uv[b0+2*FD];
    float w0 = Vv[b0], w1 = Vv[b0+FD], w2 = Vv[b0+2*FD];
    float vn  = sqrtf(w0*w0 + w1*w1 + w2*w2);
    dotb[t] = u0*w0 + u1*w1 + u2*w2;
    mbuf[(size_t)n*256 + f]      = f2b(s_mid[t]);
    mbuf[(size_t)n*256 + FD + f] = f2b(vn);
}

// ---------------- epilogue -> out slice + bf16 state for next layer ----------------
__global__ __launch_bounds__(256) void epi_kernel(
    const float* __restrict__ s_mid, const float* __restrict__ v_mid,
    const float* __restrict__ a, const float* __restrict__ dotb,
    const float* __restrict__ Uv, float* __restrict__ outp,
    u16* __restrict__ s_new_b, u16* __restrict__ v_new_b)
{
    int t = blockIdx.x * blockDim.x + threadIdx.x;   // NTOT*128
    int n = t >> 7, f = t & 127;
    float a_ss = a[(size_t)n*F3 + f];
    float a_sv = a[(size_t)n*F3 + FD + f];
    float a_vv = a[(size_t)n*F3 + 2*FD + f];
    float sval = s_mid[t] + a_ss + a_sv*dotb[t];
    outp[(size_t)n*512 + f] = sval;
    s_new_b[t] = f2b(sval);
    #pragma unroll
    for (int c=0;c<3;++c) {
        size_t vi = ((size_t)n*3 + c)*FD + f;
        float vval = v_mid[vi] + a_vv*Uv[vi];
        outp[(size_t)n*512 + (1+c)*FD + f] = vval;
        v_new_b[vi] = f2b(vval);
    }
}

extern "C" void kernel_launch(void* const* d_in, const int* in_sizes, int n_in,
                              void* d_out, int out_size, void* d_ws, size_t ws_size,
                              hipStream_t stream)
{
    (void)in_sizes; (void)n_in; (void)out_size; (void)ws_size;
    const float* atom_xyz = (const float*)d_in[0];
    const float* cell     = (const float*)d_in[1];
    const int*   nodes    = (const int*)d_in[2];
    const int*   aedges   = (const int*)d_in[3];
    const float* edisp    = (const float*)d_in[4];
    const float* V_flat   = (const float*)d_in[5];
    const float* E_flat   = (const float*)d_in[6];
    const float* atom_emb = (const float*)d_in[7];
    const float* pot_W    = (const float*)d_in[8];
    const float* pot_b    = (const float*)d_in[9];
    const float* init_W1  = (const float*)d_in[10];
    const float* init_b1  = (const float*)d_in[11];
    const float* init_W2  = (const float*)d_in[12];
    const float* init_b2  = (const float*)d_in[13];
    const float* vec_w    = (const float*)d_in[14];
    const float* filt_W   = (const float*)d_in[15];
    const float* filt_b   = (const float*)d_in[16];
    const float* msg_W1   = (const float*)d_in[17];
    const float* msg_b1   = (const float*)d_in[18];
    const float* msg_W2   = (const float*)d_in[19];
    const float* msg_b2   = (const float*)d_in[20];
    const float* U_W      = (const float*)d_in[21];
    const float* V_W      = (const float*)d_in[22];
    const float* upd_W1   = (const float*)d_in[23];
    const float* upd_b1   = (const float*)d_in[24];
    const float* upd_W2   = (const float*)d_in[25];
    const float* upd_b2   = (const float*)d_in[26];

    float* out = (float*)d_out;
    char* base = (char*)d_ws;
    size_t o = 0;
    auto alloc = [&](size_t bytes)->char* { char* r = base + o; o += (bytes + 255) & ~(size_t)255; return r; };

    float* s0     = (float*)alloc((size_t)NTOT*FD*4);
    float* v0     = (float*)alloc((size_t)NTOT*F3*4);
    float* s_mid  = (float*)alloc((size_t)NTOT*FD*4);
    float* v_mid  = (float*)alloc((size_t)NTOT*F3*4);
    float* Uv     = (float*)alloc((size_t)NTOT*F3*4);
    float* Vv     = (float*)alloc((size_t)NTOT*F3*4);   // reused as 'a' after vndot
    float* dotb   = (float*)alloc((size_t)NTOT*FD*4);
    float* esb    = (float*)alloc((size_t)ETOT*KR*4);
    float4* edata = (float4*)alloc((size_t)ETOT*16);
    u16* h_bf     = (u16*)alloc((size_t)NTOT*256*2);    // reused as mbuf
    u16* s_bf     = (u16*)alloc((size_t)NTOT*FD*2);
    u16* v_bf     = (u16*)alloc((size_t)NTOT*F3*2);
    u16* hid_bf   = (u16*)alloc((size_t)NTOT*FD*2);
    u16* so_bf    = (u16*)alloc((size_t)NTOT*F3*2);
    u16* vmid_bf  = (u16*)alloc((size_t)NTOT*F3*2);
    u16* wts      = (u16*)alloc((size_t)589824*2);
    int* sendb    = (int*)alloc((size_t)ETOT*4);
    int* recvb    = (int*)alloc((size_t)ETOT*4);
    int* row_off  = (int*)alloc((size_t)(NTOT+1)*4);
    int* counts   = (int*)alloc((size_t)NTOT*4);
    int* cursor   = (int*)alloc((size_t)NTOT*4);
    int* perm     = (int*)alloc((size_t)ETOT*4);

    hipMemsetAsync(counts, 0, NTOT*sizeof(int), stream);
    hipMemsetAsync(cursor, 0, NTOT*sizeof(int), stream);

    edge_kernel<<<ETOT/256, 256, 0, stream>>>(atom_xyz, cell, aedges, edisp,
        sendb, recvb, esb, edata, counts);
    scan_kernel<<<1, 1024, 0, stream>>>(counts, row_off);
    fill_kernel<<<ETOT/256, 256, 0, stream>>>(recvb, row_off, cursor, perm);
    wconv_kernel<<<(589824+255)/256, 256, 0, stream>>>(
        init_W1, init_W2, msg_W1, msg_W2, U_W, V_W, upd_W1, upd_W2, wts);

    // weight offsets in wts (elements)
    const u16* w_init1 = wts + 0;
    const u16* w_init2 = wts + 32768;
    const u16* w_msg1  = wts + 49152;    // 3 x 16384
    const u16* w_msg2  = wts + 98304;    // 3 x 49152
    const u16* w_U     = wts + 245760;   // 3 x 16384
    const u16* w_V     = wts + 294912;   // 3 x 16384
    const u16* w_upd1  = wts + 344064;   // 3 x 32768
    const u16* w_upd2  = wts + 442368;   // 3 x 49152

    hbuild_kernel<<<NTOT*256/256, 256, 0, stream>>>(nodes, atom_emb, V_flat, pot_W, pot_b, h_bf);
    bgemm_kernel<1><<<dim3(FD/64, NTOT/64), 256, 0, stream>>>(
        h_bf, 256, w_init1, 256, init_b1, (float*)nullptr, 0, hid_bf, FD);
    bgemm_kernel<0><<<dim3(FD/64, NTOT/64), 256, 0, stream>>>(
        hid_bf, FD, w_init2, FD, init_b2, s0, FD, s_bf, FD);
    v0_kernel<<<NTOT*F3/256, 256, 0, stream>>>(E_flat, vec_w, v0, v_bf);

    const float* s_prev_f = s0;  int s_ldaf  = FD;
    const float* v_prev_f = v0;  int v_nstrf = 3*FD;
    for (int l = 0; l < 3; ++l) {
        bgemm_kernel<1><<<dim3(FD/64, NTOT/64), 256, 0, stream>>>(
            s_bf, FD, w_msg1 + (size_t)l*16384, FD, msg_b1 + (size_t)l*FD,
            (float*)nullptr, 0, hid_bf, FD);
        bgemm_kernel<0><<<dim3(F3/64, NTOT/64), 256, 0, stream>>>(
            hid_bf, FD, w_msg2 + (size_t)l*49152, FD, msg_b2 + (size_t)l*F3,
            (float*)nullptr, 0, so_bf, F3);
        agg_kernel<<<2048, 256, 0, stream>>>(s_prev_f, s_ldaf, v_prev_f, v_nstrf,
            s_bf, v_bf, so_bf, esb, edata, row_off, perm, sendb,
            filt_W + (size_t)l*F3*KR, filt_b + (size_t)l*F3, s_mid, v_mid, vmid_bf);
        bgemm_kernel<0><<<dim3(FD/64, 3*NTOT/64), 256, 0, stream>>>(
            vmid_bf, FD, w_U + (size_t)l*16384, FD, (const float*)nullptr,
            Uv, FD, (u16*)nullptr, 0);
        bgemm_kernel<0><<<dim3(FD/64, 3*NTOT/64), 256, 0, stream>>>(
            vmid_bf, FD, w_V + (size_t)l*16384, FD, (const float*)nullptr,
            Vv, FD, (u16*)nullptr, 0);
        vndot_kernel<<<NTOT*FD/256, 256, 0, stream>>>(Uv, Vv, s_mid, h_bf, dotb);
        bgemm_kernel<1><<<dim3(FD/64, NTOT/64), 256, 0, stream>>>(
            h_bf, 256, w_upd1 + (size_t)l*32768, 256, upd_b1 + (size_t)l*FD,
            (float*)nullptr, 0, hid_bf, FD);
        bgemm_kernel<0><<<dim3(F3/64, NTOT/64), 256, 0, stream>>>(
            hid_bf, FD, w_upd2 + (size_t)l*49152, FD, upd_b2 + (size_t)l*F3,
            Vv, F3, (u16*)nullptr, 0);   // Vv reused as 'a'
        float* outp = out + (size_t)l*NTOT*512;
        epi_kernel<<<NTOT*FD/256, 256, 0, stream>>>(s_mid, v_mid, Vv, dotb, Uv, outp,
            s_bf, v_bf);
        s_prev_f = outp;        s_ldaf  = 512;
        v_prev_f = outp + FD;   v_nstrf = 512;
    }
}

// Round 3
// 1314.955 us; speedup vs baseline: 1.2395x; 1.2395x over previous
//
#include <hip/hip_runtime.h>
#include <math.h>

#define NPER  4096
#define NTOT  16384
#define EPER  49152
#define ETOT  196608
#define FD    128
#define F3    384
#define KR    20
#define PI_F  3.14159265358979f

typedef unsigned short u16;
typedef __attribute__((ext_vector_type(8))) short s16x8;
typedef __attribute__((ext_vector_type(4))) float f32x4;

__device__ __forceinline__ float silu_f(float x){ return x / (1.0f + __expf(-x)); }
__device__ __forceinline__ u16 f2b(float x){
    unsigned u = __float_as_uint(x);
    u = u + 0x7FFFu + ((u >> 16) & 1u);
    return (u16)(u >> 16);
}
__device__ __forceinline__ float b2f(u16 h){ return __uint_as_float(((unsigned)h) << 16); }

// ---------------- edge precompute (indexed by e) ----------------
__global__ __launch_bounds__(256) void edge_kernel(
    const float* __restrict__ xyz, const float* __restrict__ cell,
    const int* __restrict__ aedges, const float* __restrict__ edisp,
    int* __restrict__ sendb, int* __restrict__ recvb,
    float* __restrict__ esb, float4* __restrict__ edata,
    int* __restrict__ counts)
{
    int e = blockIdx.x * blockDim.x + threadIdx.x;
    if (e >= ETOT) return;
    int b = e / EPER;
    int s = aedges[(size_t)e*2+0] + b*NPER;
    int r = aedges[(size_t)e*2+1] + b*NPER;
    const float* cb = cell + b*9;
    float c0 = edisp[(size_t)e*3+0], c1 = edisp[(size_t)e*3+1], c2 = edisp[(size_t)e*3+2];
    float diff[3];
    #pragma unroll
    for (int d=0; d<3; ++d) {
        float disp = c0*cb[d] + c1*cb[3+d] + c2*cb[6+d];
        diff[d] = xyz[(size_t)r*3+d] - (xyz[(size_t)s*3+d] + disp);
    }
    float dist = sqrtf(diff[0]*diff[0]+diff[1]*diff[1]+diff[2]*diff[2]);
    float cut = (dist < 5.0f) ? 0.5f*(cosf(PI_F*dist*0.2f)+1.0f) : 0.0f;
    float invg = 1.0f/fmaxf(dist,1e-12f);
    edata[e] = make_float4(diff[0]*invg, diff[1]*invg, diff[2]*invg, cut);
    float invd = 1.0f/dist;
    float ang = dist*(PI_F*0.2f);
    #pragma unroll
    for (int k=0;k<KR;++k) esb[(size_t)e*KR+k] = sinf(ang*(float)(k+1))*invd;
    sendb[e]=s; recvb[e]=r;
    atomicAdd(&counts[r],1);
}

// ---------------- exclusive scan counts -> row_off ----------------
__global__ __launch_bounds__(1024) void scan_kernel(const int* __restrict__ counts,
                                                    int* __restrict__ row_off)
{
    __shared__ int sdata[1024];
    int t = threadIdx.x;
    int base = t * 16;
    int local[16];
    int s = 0;
    #pragma unroll
    for (int i=0;i<16;++i){ local[i]=s; s += counts[base+i]; }
    sdata[t] = s;
    __syncthreads();
    for (int off=1; off<1024; off<<=1) {
        int val = (t>=off) ? sdata[t-off] : 0;
        __syncthreads();
        sdata[t] += val;
        __syncthreads();
    }
    int chunk_off = (t==0) ? 0 : sdata[t-1];
    #pragma unroll
    for (int i=0;i<16;++i) row_off[base+i] = chunk_off + local[i];
    if (t==1023) row_off[NTOT] = sdata[1023];
}

// ---------------- CSR fill: permute edge payloads into recv-sorted order ----------------
__global__ __launch_bounds__(256) void fill_kernel(
    const int* __restrict__ recvb, const int* __restrict__ sendb,
    const float* __restrict__ esb, const float4* __restrict__ edata,
    const int* __restrict__ row_off, int* __restrict__ cursor,
    int* __restrict__ sd_csr, float4* __restrict__ es_csr, float4* __restrict__ ed_csr)
{
    int e = blockIdx.x * blockDim.x + threadIdx.x;
    if (e >= ETOT) return;
    int r = recvb[e];
    int slot = atomicAdd(&cursor[r], 1);
    int pos = row_off[r] + slot;
    sd_csr[pos] = sendb[e];
    ed_csr[pos] = edata[e];
    const float4* src = (const float4*)(esb + (size_t)e*KR);
    float4* dst = es_csr + (size_t)pos*5;
    #pragma unroll
    for (int i=0;i<5;++i) dst[i] = src[i];
}

// ---------------- weight fp32 -> bf16 conversion ----------------
__global__ __launch_bounds__(256) void wconv_kernel(
    const float* __restrict__ w0, const float* __restrict__ w1,
    const float* __restrict__ w2, const float* __restrict__ w3,
    const float* __restrict__ w4, const float* __restrict__ w5,
    const float* __restrict__ w6, const float* __restrict__ w7,
    u16* __restrict__ dst)
{
    int t = blockIdx.x*256 + threadIdx.x;
    if (t >= 589824) return;
    const float* src; int off;
    if      (t < 32768)  { src=w0; off=t; }
    else if (t < 49152)  { src=w1; off=t-32768; }
    else if (t < 98304)  { src=w2; off=t-49152; }
    else if (t < 245760) { src=w3; off=t-98304; }
    else if (t < 294912) { src=w4; off=t-245760; }
    else if (t < 344064) { src=w5; off=t-294912; }
    else if (t < 442368) { src=w6; off=t-344064; }
    else                 { src=w7; off=t-442368; }
    dst[t] = f2b(src[off]);
}

// ---------------- h = [atom_emb[nodes], V*potW + potb] -> bf16 ----------------
__global__ __launch_bounds__(256) void hbuild_kernel(const int* __restrict__ nodes,
    const float* __restrict__ atom_emb, const float* __restrict__ V_flat,
    const float* __restrict__ pot_W, const float* __restrict__ pot_b,
    u16* __restrict__ h)
{
    int t = blockIdx.x * blockDim.x + threadIdx.x;   // NTOT*256
    int n = t >> 8, k = t & 255;
    float val;
    if (k < FD) val = atom_emb[(size_t)nodes[n]*FD + k];
    else { int f = k - FD; val = V_flat[n]*pot_W[f] + pot_b[f]; }
    h[t] = f2b(val);
}

// ---------------- v0 = E_flat[:,c] * vec_w[f] (fp32 + vq quad) ----------------
__global__ __launch_bounds__(256) void v0_kernel(const float* __restrict__ E_flat,
    const float* __restrict__ vec_w, float* __restrict__ v0, u16* __restrict__ vq)
{
    int t = blockIdx.x * blockDim.x + threadIdx.x;   // NTOT*384
    int n = t / F3, r = t - n*F3;
    int c = r >> 7, f = r & 127;
    float val = E_flat[(size_t)n*3 + c] * vec_w[f];
    v0[t] = val;
    vq[((size_t)n*FD + f)*4 + c] = f2b(val);
}

// ---------------- bf16 MFMA GEMM: C[MxN] = act(A[MxK] @ W[NxK]^T + b) ----------------
// 256 threads = 4 waves; wave w: rows [by*64+w*16,+16) x cols [bx*64,+64).
// Cq: quad-remap store Cq[(row*128 + (col&127))*4 + (col>>7) + qoff]
template<int ACT>
__global__ __launch_bounds__(256) void bgemm_kernel(
    const u16* __restrict__ A, int lda,
    const u16* __restrict__ W, int Kdim,
    const float* __restrict__ bias,
    float* __restrict__ C, int ldc,
    u16* __restrict__ Cb, int ldcb,
    u16* __restrict__ Cq, int qoff)
{
    const int tid  = threadIdx.x;
    const int wave = tid >> 6, lane = tid & 63;
    const int q = lane >> 4, im = lane & 15;
    const int row0 = blockIdx.y*64 + wave*16;
    const int col0 = blockIdx.x*64;
    f32x4 acc[4];
    #pragma unroll
    for (int n=0;n<4;++n) acc[n] = (f32x4){0.f,0.f,0.f,0.f};
    const u16* Ap = A + (size_t)(row0+im)*lda + q*8;
    const u16* Wp = W + (size_t)(col0+im)*Kdim + q*8;
    for (int k0 = 0; k0 < Kdim; k0 += 32) {
        s16x8 af = *(const s16x8*)(Ap + k0);
        #pragma unroll
        for (int n=0;n<4;++n) {
            s16x8 bf = *(const s16x8*)(Wp + (size_t)n*16*Kdim + k0);
            acc[n] = __builtin_amdgcn_mfma_f32_16x16x32_bf16(af, bf, acc[n], 0, 0, 0);
        }
    }
    #pragma unroll
    for (int n=0;n<4;++n) {
        int col = col0 + n*16 + im;
        float bv = bias ? bias[col] : 0.f;
        #pragma unroll
        for (int r=0;r<4;++r) {
            int row = row0 + q*4 + r;
            float v = acc[n][r] + bv;
            if (ACT) v = silu_f(v);
            if (C)  C[(size_t)row*ldc + col] = v;
            if (Cb) Cb[(size_t)row*ldcb + col] = f2b(v);
            if (Cq) Cq[((size_t)row*FD + (col & 127))*4 + (col >> 7) + qoff] = f2b(v);
        }
    }
}

// ---------------- agg helpers ----------------
__device__ __forceinline__ float dot20(const float4* e, const float4* w){
    float d = 0.f;
    #pragma unroll
    for (int i=0;i<5;++i)
        d += e[i].x*w[i].x + e[i].y*w[i].y + e[i].z*w[i].z + e[i].w*w[i].w;
    return d;
}
__device__ __forceinline__ void edge_step(
    const float4* es, float4 ed, ushort4 s4, ushort4 v4,
    const float4* w0, const float4* w1, const float4* w2,
    float b0, float b1, float b2,
    float& acc_s, float& av0, float& av1, float& av2)
{
    float g_sv = (dot20(es, w0) + b0) * ed.w;
    float g_ev = (dot20(es, w1) + b1) * ed.w;
    float g_ns = (dot20(es, w2) + b2) * ed.w;
    float fo_sv = g_sv * b2f(s4.x);
    float fo_ev = g_ev * b2f(s4.y);
    float fo_ns = g_ns * b2f(s4.z);
    acc_s += b2f(s4.w) * fo_ns;
    av0 += b2f(v4.x)*fo_sv + fo_ev*ed.x;
    av1 += b2f(v4.y)*fo_sv + fo_ev*ed.y;
    av2 += b2f(v4.z)*fo_sv + fo_ev*ed.z;
}

// ---------------- fused filter + gather aggregation ----------------
// 256 threads: f = tid&127, sub = tid>>7. Filter weights in registers
// (launch_bounds (256,3) -> VGPR cap ~168, no spill). CSR payloads are
// pre-permuted (sequential reads); gathers are two 8B quads per edge.
__global__ __launch_bounds__(256, 3) void agg_kernel(
    const float* __restrict__ s_prev_f, int s_ldaf,
    const float* __restrict__ v_prev_f, int v_nstrf,
    const ushort4* __restrict__ sq, const ushort4* __restrict__ vq,
    const float4* __restrict__ es_csr, const float4* __restrict__ ed_csr,
    const int* __restrict__ sd_csr, const int* __restrict__ row_off,
    const float* __restrict__ fW, const float* __restrict__ fb,
    float* __restrict__ s_mid, float* __restrict__ v_mid, u16* __restrict__ vmid_bf)
{
    const int f   = threadIdx.x & 127;
    const int sub = threadIdx.x >> 7;
    float4 w0[5], w1[5], w2[5];
    {
        const float4* p0 = (const float4*)(fW + (size_t)f*KR);
        const float4* p1 = (const float4*)(fW + (size_t)(FD+f)*KR);
        const float4* p2 = (const float4*)(fW + (size_t)(2*FD+f)*KR);
        #pragma unroll
        for (int i=0;i<5;++i){ w0[i]=p0[i]; w1[i]=p1[i]; w2[i]=p2[i]; }
    }
    const float b0 = fb[f], b1 = fb[FD+f], b2 = fb[2*FD+f];

    for (int n = blockIdx.x*2 + sub; n < NTOT; n += gridDim.x*2) {
        int beg = row_off[n], end = row_off[n+1];
        float acc_s=0.f, av0=0.f, av1=0.f, av2=0.f;
        int idx = beg;
        for (; idx + 2 <= end; idx += 2) {
            int sdA = sd_csr[idx], sdB = sd_csr[idx+1];
            ushort4 sA = sq[(size_t)sdA*FD + f];
            ushort4 sB = sq[(size_t)sdB*FD + f];
            ushort4 vA = vq[(size_t)sdA*FD + f];
            ushort4 vB = vq[(size_t)sdB*FD + f];
            float4 edA = ed_csr[idx], edB = ed_csr[idx+1];
            float4 eA[5], eB[5];
            const float4* epA = es_csr + (size_t)idx*5;
            #pragma unroll
            for (int i=0;i<5;++i){ eA[i]=epA[i]; eB[i]=epA[5+i]; }
            edge_step(eA, edA, sA, vA, w0,w1,w2, b0,b1,b2, acc_s, av0, av1, av2);
            edge_step(eB, edB, sB, vB, w0,w1,w2, b0,b1,b2, acc_s, av0, av1, av2);
        }
        if (idx < end) {
            int sdA = sd_csr[idx];
            ushort4 sA = sq[(size_t)sdA*FD + f];
            ushort4 vA = vq[(size_t)sdA*FD + f];
            float4 edA = ed_csr[idx];
            float4 eA[5];
            const float4* epA = es_csr + (size_t)idx*5;
            #pragma unroll
            for (int i=0;i<5;++i) eA[i]=epA[i];
            edge_step(eA, edA, sA, vA, w0,w1,w2, b0,b1,b2, acc_s, av0, av1, av2);
        }
        s_mid[(size_t)n*FD+f] = s_prev_f[(size_t)n*s_ldaf+f] + acc_s;
        const float* vp = v_prev_f + (size_t)n*v_nstrf;
        float o0 = vp[f]+av0, o1 = vp[FD+f]+av1, o2 = vp[2*FD+f]+av2;
        size_t vo = (size_t)n*F3;
        v_mid[vo+f]=o0;        v_mid[vo+FD+f]=o1;        v_mid[vo+2*FD+f]=o2;
        vmid_bf[vo+f]=f2b(o0); vmid_bf[vo+FD+f]=f2b(o1); vmid_bf[vo+2*FD+f]=f2b(o2);
    }
}

// ---------------- Vn, dot(Uv,Vv); m = [s_mid, Vn] (bf16) ----------------
__global__ __launch_bounds__(256) void vndot_kernel(
    const float* __restrict__ Uv, const float* __restrict__ Vv,
    const float* __restrict__ s_mid,
    u16* __restrict__ mbuf, float* __restrict__ dotb)
{
    int t = blockIdx.x * blockDim.x + threadIdx.x;   // NTOT*128
    int n = t >> 7, f = t & 127;
    size_t b0 = (size_t)n*3*FD + f;
    float u0 = Uv[b0], u1 = Uv[b0+FD], u2 = Uv[b0+2*FD];
    float w0 = Vv[b0], w1 = Vv[b0+FD], w2 = Vv[b0+2*FD];
    float vn  = sqrtf(w0*w0 + w1*w1 + w2*w2);
    dotb[t] = u0*w0 + u1*w1 + u2*w2;
    mbuf[(size_t)n*256 + f]      = f2b(s_mid[t]);
    mbuf[(size_t)n*256 + FD + f] = f2b(vn);
}

// ---------------- epilogue -> out slice + bf16/quad state for next layer ----------------
__global__ __launch_bounds__(256) void epi_kernel(
    const float* __restrict__ s_mid, const float* __restrict__ v_mid,
    const float* __restrict__ a, const float* __restrict__ dotb,
    const float* __restrict__ Uv, float* __restrict__ outp,
    u16* __restrict__ s_new_b, u16* __restrict__ sq, u16* __restrict__ vq)
{
    int t = blockIdx.x * blockDim.x + threadIdx.x;   // NTOT*128
    int n = t >> 7, f = t & 127;
    float a_ss = a[(size_t)n*F3 + f];
    float a_sv = a[(size_t)n*F3 + FD + f];
    float a_vv = a[(size_t)n*F3 + 2*FD + f];
    float sval = s_mid[t] + a_ss + a_sv*dotb[t];
    outp[(size_t)n*512 + f] = sval;
    s_new_b[t] = f2b(sval);
    sq[(size_t)t*4 + 3] = f2b(sval);
    #pragma unroll
    for (int c=0;c<3;++c) {
        size_t vi = ((size_t)n*3 + c)*FD + f;
        float vval = v_mid[vi] + a_vv*Uv[vi];
        outp[(size_t)n*512 + (1+c)*FD + f] = vval;
        vq[(size_t)t*4 + c] = f2b(vval);
    }
}

extern "C" void kernel_launch(void* const* d_in, const int* in_sizes, int n_in,
                              void* d_out, int out_size, void* d_ws, size_t ws_size,
                              hipStream_t stream)
{
    (void)in_sizes; (void)n_in; (void)out_size; (void)ws_size;
    const float* atom_xyz = (const float*)d_in[0];
    const float* cell     = (const float*)d_in[1];
    const int*   nodes    = (const int*)d_in[2];
    const int*   aedges   = (const int*)d_in[3];
    const float* edisp    = (const float*)d_in[4];
    const float* V_flat   = (const float*)d_in[5];
    const float* E_flat   = (const float*)d_in[6];
    const float* atom_emb = (const float*)d_in[7];
    const float* pot_W    = (const float*)d_in[8];
    const float* pot_b    = (const float*)d_in[9];
    const float* init_W1  = (const float*)d_in[10];
    const float* init_b1  = (const float*)d_in[11];
    const float* init_W2  = (const float*)d_in[12];
    const float* init_b2  = (const float*)d_in[13];
    const float* vec_w    = (const float*)d_in[14];
    const float* filt_W   = (const float*)d_in[15];
    const float* filt_b   = (const float*)d_in[16];
    const float* msg_W1   = (const float*)d_in[17];
    const float* msg_b1   = (const float*)d_in[18];
    const float* msg_W2   = (const float*)d_in[19];
    const float* msg_b2   = (const float*)d_in[20];
    const float* U_W      = (const float*)d_in[21];
    const float* V_W      = (const float*)d_in[22];
    const float* upd_W1   = (const float*)d_in[23];
    const float* upd_b1   = (const float*)d_in[24];
    const float* upd_W2   = (const float*)d_in[25];
    const float* upd_b2   = (const float*)d_in[26];

    float* out = (float*)d_out;
    char* base = (char*)d_ws;
    size_t o = 0;
    auto alloc = [&](size_t bytes)->char* { char* r = base + o; o += (bytes + 255) & ~(size_t)255; return r; };

    float* s0     = (float*)alloc((size_t)NTOT*FD*4);
    float* v0     = (float*)alloc((size_t)NTOT*F3*4);
    float* s_mid  = (float*)alloc((size_t)NTOT*FD*4);
    float* v_mid  = (float*)alloc((size_t)NTOT*F3*4);
    float* Uv     = (float*)alloc((size_t)NTOT*F3*4);
    float* Vv     = (float*)alloc((size_t)NTOT*F3*4);   // reused as 'a'
    float* dotb   = (float*)alloc((size_t)NTOT*FD*4);
    float* esb    = (float*)alloc((size_t)ETOT*KR*4);
    float4* edata = (float4*)alloc((size_t)ETOT*16);
    float4* es_csr= (float4*)alloc((size_t)ETOT*KR*4);
    float4* ed_csr= (float4*)alloc((size_t)ETOT*16);
    u16* h_bf     = (u16*)alloc((size_t)NTOT*256*2);    // reused as mbuf
    u16* s_bf     = (u16*)alloc((size_t)NTOT*FD*2);
    u16* sq       = (u16*)alloc((size_t)NTOT*FD*4*2);   // quads {so0,so1,so2,s}
    u16* vq       = (u16*)alloc((size_t)NTOT*FD*4*2);   // quads {v0,v1,v2,-}
    u16* hid_bf   = (u16*)alloc((size_t)NTOT*FD*2);
    u16* vmid_bf  = (u16*)alloc((size_t)NTOT*F3*2);
    u16* wts      = (u16*)alloc((size_t)589824*2);
    int* sendb    = (int*)alloc((size_t)ETOT*4);
    int* recvb    = (int*)alloc((size_t)ETOT*4);
    int* sd_csr   = (int*)alloc((size_t)ETOT*4);
    int* row_off  = (int*)alloc((size_t)(NTOT+1)*4);
    int* counts   = (int*)alloc((size_t)NTOT*4);
    int* cursor   = (int*)alloc((size_t)NTOT*4);

    hipMemsetAsync(counts, 0, NTOT*sizeof(int), stream);
    hipMemsetAsync(cursor, 0, NTOT*sizeof(int), stream);

    edge_kernel<<<ETOT/256, 256, 0, stream>>>(atom_xyz, cell, aedges, edisp,
        sendb, recvb, esb, edata, counts);
    scan_kernel<<<1, 1024, 0, stream>>>(counts, row_off);
    fill_kernel<<<ETOT/256, 256, 0, stream>>>(recvb, sendb, esb, edata,
        row_off, cursor, sd_csr, es_csr, ed_csr);
    wconv_kernel<<<(589824+255)/256, 256, 0, stream>>>(
        init_W1, init_W2, msg_W1, msg_W2, U_W, V_W, upd_W1, upd_W2, wts);

    const u16* w_init1 = wts + 0;
    const u16* w_init2 = wts + 32768;
    const u16* w_msg1  = wts + 49152;    // 3 x 16384
    const u16* w_msg2  = wts + 98304;    // 3 x 49152
    const u16* w_U     = wts + 245760;   // 3 x 16384
    const u16* w_V     = wts + 294912;   // 3 x 16384
    const u16* w_upd1  = wts + 344064;   // 3 x 32768
    const u16* w_upd2  = wts + 442368;   // 3 x 49152

    hbuild_kernel<<<NTOT*256/256, 256, 0, stream>>>(nodes, atom_emb, V_flat, pot_W, pot_b, h_bf);
    bgemm_kernel<1><<<dim3(FD/64, NTOT/64), 256, 0, stream>>>(
        h_bf, 256, w_init1, 256, init_b1, (float*)nullptr, 0, hid_bf, FD, (u16*)nullptr, 0);
    bgemm_kernel<0><<<dim3(FD/64, NTOT/64), 256, 0, stream>>>(
        hid_bf, FD, w_init2, FD, init_b2, s0, FD, s_bf, FD, sq, 3);
    v0_kernel<<<NTOT*F3/256, 256, 0, stream>>>(E_flat, vec_w, v0, vq);

    const float* s_prev_f = s0;  int s_ldaf  = FD;
    const float* v_prev_f = v0;  int v_nstrf = 3*FD;
    for (int l = 0; l < 3; ++l) {
        bgemm_kernel<1><<<dim3(FD/64, NTOT/64), 256, 0, stream>>>(
            s_bf, FD, w_msg1 + (size_t)l*16384, FD, msg_b1 + (size_t)l*FD,
            (float*)nullptr, 0, hid_bf, FD, (u16*)nullptr, 0);
        bgemm_kernel<0><<<dim3(F3/64, NTOT/64), 256, 0, stream>>>(
            hid_bf, FD, w_msg2 + (size_t)l*49152, FD, msg_b2 + (size_t)l*F3,
            (float*)nullptr, 0, (u16*)nullptr, 0, sq, 0);
        agg_kernel<<<2048, 256, 0, stream>>>(s_prev_f, s_ldaf, v_prev_f, v_nstrf,
            (const ushort4*)sq, (const ushort4*)vq, es_csr, ed_csr, sd_csr, row_off,
            filt_W + (size_t)l*F3*KR, filt_b + (size_t)l*F3, s_mid, v_mid, vmid_bf);
        bgemm_kernel<0><<<dim3(FD/64, 3*NTOT/64), 256, 0, stream>>>(
            vmid_bf, FD, w_U + (size_t)l*16384, FD, (const float*)nullptr,
            Uv, FD, (u16*)nullptr, 0, (u16*)nullptr, 0);
        bgemm_kernel<0><<<dim3(FD/64, 3*NTOT/64), 256, 0, stream>>>(
            vmid_bf, FD, w_V + (size_t)l*16384, FD, (const float*)nullptr,
            Vv, FD, (u16*)nullptr, 0, (u16*)nullptr, 0);
        vndot_kernel<<<NTOT*FD/256, 256, 0, stream>>>(Uv, Vv, s_mid, h_bf, dotb);
        bgemm_kernel<1><<<dim3(FD/64, NTOT/64), 256, 0, stream>>>(
            h_bf, 256, w_upd1 + (size_t)l*32768, 256, upd_b1 + (size_t)l*FD,
            (float*)nullptr, 0, hid_bf, FD, (u16*)nullptr, 0);
        bgemm_kernel<0><<<dim3(F3/64, NTOT/64), 256, 0, stream>>>(
            hid_bf, FD, w_upd2 + (size_t)l*49152, FD, upd_b2 + (size_t)l*F3,
            Vv, F3, (u16*)nullptr, 0, (u16*)nullptr, 0);   // Vv reused as 'a'
        float* outp = out + (size_t)l*NTOT*512;
        epi_kernel<<<NTOT*FD/256, 256, 0, stream>>>(s_mid, v_mid, Vv, dotb, Uv, outp,
            s_bf, sq, vq);
        s_prev_f = outp;        s_ldaf  = 512;
        v_prev_f = outp + FD;   v_nstrf = 512;
    }
}

// Round 4
// 968.597 us; speedup vs baseline: 1.6827x; 1.3576x over previous
//
#include <hip/hip_runtime.h>
#include <math.h>

#define NPER  4096
#define NTOT  16384
#define EPER  49152
#define ETOT  196608
#define FD    128
#define F3    384
#define KR    20
#define PI_F  3.14159265358979f

typedef unsigned short u16;
typedef __attribute__((ext_vector_type(8))) short s16x8;
typedef __attribute__((ext_vector_type(4))) float f32x4;
typedef _Float16 h16x2 __attribute__((ext_vector_type(2)));
typedef _Float16 h16x4 __attribute__((ext_vector_type(4)));
typedef _Float16 h16x8 __attribute__((ext_vector_type(8)));

#if defined(__has_builtin)
#if __has_builtin(__builtin_amdgcn_fdot2)
#define FDOT2(a,b,c) __builtin_amdgcn_fdot2((a),(b),(c),false)
#endif
#endif
#ifndef FDOT2
#define FDOT2(a,b,c) ((float)(a)[0]*(float)(b)[0] + (float)(a)[1]*(float)(b)[1] + (c))
#endif

__device__ __forceinline__ float silu_f(float x){ return x / (1.0f + __expf(-x)); }
__device__ __forceinline__ u16 f2b(float x){
    unsigned u = __float_as_uint(x);
    u = u + 0x7FFFu + ((u >> 16) & 1u);
    return (u16)(u >> 16);
}
__device__ __forceinline__ float b2f(u16 h){ return __uint_as_float(((unsigned)h) << 16); }

// 64B edge record: {dirn.xyz, cut} + 20 f16 of es*cut (RBF pre-scaled by cutoff)
struct __align__(16) EdgeRec {
    float4 ed;
    h16x8  es0;   // pairs 0-3
    h16x8  es1;   // pairs 4-7
    h16x4  es2;   // pairs 8-9
    h16x4  pad;
};

// ---------------- edge precompute ----------------
__global__ __launch_bounds__(256) void edge_kernel(
    const float* __restrict__ xyz, const float* __restrict__ cell,
    const int* __restrict__ aedges, const float* __restrict__ edisp,
    int* __restrict__ sendb, int* __restrict__ recvb,
    EdgeRec* __restrict__ erec, int* __restrict__ counts)
{
    int e = blockIdx.x * blockDim.x + threadIdx.x;
    if (e >= ETOT) return;
    int b = e / EPER;
    int s = aedges[(size_t)e*2+0] + b*NPER;
    int r = aedges[(size_t)e*2+1] + b*NPER;
    const float* cb = cell + b*9;
    float c0 = edisp[(size_t)e*3+0], c1 = edisp[(size_t)e*3+1], c2 = edisp[(size_t)e*3+2];
    float diff[3];
    #pragma unroll
    for (int d=0; d<3; ++d) {
        float disp = c0*cb[d] + c1*cb[3+d] + c2*cb[6+d];
        diff[d] = xyz[(size_t)r*3+d] - (xyz[(size_t)s*3+d] + disp);
    }
    float dist = sqrtf(diff[0]*diff[0]+diff[1]*diff[1]+diff[2]*diff[2]);
    float cut = (dist < 5.0f) ? 0.5f*(__cosf(PI_F*dist*0.2f)+1.0f) : 0.0f;
    float invg = 1.0f/fmaxf(dist,1e-12f);
    EdgeRec rec;
    rec.ed = make_float4(diff[0]*invg, diff[1]*invg, diff[2]*invg, cut);
    // sin(k*theta) via Chebyshev recurrence; store es*cut in f16
    float theta = dist*(PI_F*0.2f);
    float s1 = __sinf(theta), cth = __cosf(theta);
    float scale = cut / dist;
    float twoc = 2.f*cth;
    float sm1 = 0.f, sk = s1;
    _Float16 esv[20];
    #pragma unroll
    for (int k=0;k<20;++k){
        esv[k] = (_Float16)(sk*scale);
        float nx = twoc*sk - sm1;
        sm1 = sk; sk = nx;
    }
    union { h16x8 v; _Float16 h[8]; } u0, u1;
    union { h16x4 v; _Float16 h[4]; } u2;
    #pragma unroll
    for (int i=0;i<8;++i){ u0.h[i]=esv[i]; u1.h[i]=esv[8+i]; }
    #pragma unroll
    for (int i=0;i<4;++i) u2.h[i]=esv[16+i];
    rec.es0=u0.v; rec.es1=u1.v; rec.es2=u2.v;
    rec.pad = (h16x4)((_Float16)0);
    erec[e] = rec;
    sendb[e]=s; recvb[e]=r;
    atomicAdd(&counts[r],1);
}

// ---------------- exclusive scan counts -> row_off ----------------
__global__ __launch_bounds__(1024) void scan_kernel(const int* __restrict__ counts,
                                                    int* __restrict__ row_off)
{
    __shared__ int sdata[1024];
    int t = threadIdx.x;
    int base = t * 16;
    int local[16];
    int s = 0;
    #pragma unroll
    for (int i=0;i<16;++i){ local[i]=s; s += counts[base+i]; }
    sdata[t] = s;
    __syncthreads();
    for (int off=1; off<1024; off<<=1) {
        int val = (t>=off) ? sdata[t-off] : 0;
        __syncthreads();
        sdata[t] += val;
        __syncthreads();
    }
    int chunk_off = (t==0) ? 0 : sdata[t-1];
    #pragma unroll
    for (int i=0;i<16;++i) row_off[base+i] = chunk_off + local[i];
    if (t==1023) row_off[NTOT] = sdata[1023];
}

// ---------------- CSR fill: permute edge records into recv-sorted order ----------------
__global__ __launch_bounds__(256) void fill_kernel(
    const int* __restrict__ recvb, const int* __restrict__ sendb,
    const EdgeRec* __restrict__ erec,
    const int* __restrict__ row_off, int* __restrict__ cursor,
    int* __restrict__ sd_csr, EdgeRec* __restrict__ erec_csr)
{
    int e = blockIdx.x * blockDim.x + threadIdx.x;
    if (e >= ETOT) return;
    int r = recvb[e];
    int slot = atomicAdd(&cursor[r], 1);
    int pos = row_off[r] + slot;
    sd_csr[pos] = sendb[e];
    erec_csr[pos] = erec[e];
}

// ---------------- weight fp32 -> bf16 conversion ----------------
__global__ __launch_bounds__(256) void wconv_kernel(
    const float* __restrict__ w0, const float* __restrict__ w1,
    const float* __restrict__ w2, const float* __restrict__ w3,
    const float* __restrict__ w4, const float* __restrict__ w5,
    const float* __restrict__ w6, const float* __restrict__ w7,
    u16* __restrict__ dst)
{
    int t = blockIdx.x*256 + threadIdx.x;
    if (t >= 589824) return;
    const float* src; int off;
    if      (t < 32768)  { src=w0; off=t; }
    else if (t < 49152)  { src=w1; off=t-32768; }
    else if (t < 98304)  { src=w2; off=t-49152; }
    else if (t < 245760) { src=w3; off=t-98304; }
    else if (t < 294912) { src=w4; off=t-245760; }
    else if (t < 344064) { src=w5; off=t-294912; }
    else if (t < 442368) { src=w6; off=t-344064; }
    else                 { src=w7; off=t-442368; }
    dst[t] = f2b(src[off]);
}

// ---------------- filter weights fp32 -> f16 ----------------
__global__ __launch_bounds__(256) void wfilt_kernel(const float* __restrict__ fW,
                                                    _Float16* __restrict__ dst)
{
    int t = blockIdx.x*256 + threadIdx.x;
    if (t < 3*F3*KR) dst[t] = (_Float16)fW[t];
}

// ---------------- h = [atom_emb[nodes], V*potW + potb] -> bf16 ----------------
__global__ __launch_bounds__(256) void hbuild_kernel(const int* __restrict__ nodes,
    const float* __restrict__ atom_emb, const float* __restrict__ V_flat,
    const float* __restrict__ pot_W, const float* __restrict__ pot_b,
    u16* __restrict__ h)
{
    int t = blockIdx.x * blockDim.x + threadIdx.x;   // NTOT*256
    int n = t >> 8, k = t & 255;
    float val;
    if (k < FD) val = atom_emb[(size_t)nodes[n]*FD + k];
    else { int f = k - FD; val = V_flat[n]*pot_W[f] + pot_b[f]; }
    h[t] = f2b(val);
}

// ---------------- v0 = E_flat[:,c] * vec_w[f] (fp32 + vq quad) ----------------
__global__ __launch_bounds__(256) void v0_kernel(const float* __restrict__ E_flat,
    const float* __restrict__ vec_w, float* __restrict__ v0, u16* __restrict__ vq)
{
    int t = blockIdx.x * blockDim.x + threadIdx.x;   // NTOT*384
    int n = t / F3, r = t - n*F3;
    int c = r >> 7, f = r & 127;
    float val = E_flat[(size_t)n*3 + c] * vec_w[f];
    v0[t] = val;
    vq[((size_t)n*FD + f)*4 + c] = f2b(val);
}

// ---------------- bf16 MFMA GEMM ----------------
template<int ACT>
__global__ __launch_bounds__(256) void bgemm_kernel(
    const u16* __restrict__ A, int lda,
    const u16* __restrict__ W, int Kdim,
    const float* __restrict__ bias,
    float* __restrict__ C, int ldc,
    u16* __restrict__ Cb, int ldcb,
    u16* __restrict__ Cq, int qoff)
{
    const int tid  = threadIdx.x;
    const int wave = tid >> 6, lane = tid & 63;
    const int q = lane >> 4, im = lane & 15;
    const int row0 = blockIdx.y*64 + wave*16;
    const int col0 = blockIdx.x*64;
    f32x4 acc[4];
    #pragma unroll
    for (int n=0;n<4;++n) acc[n] = (f32x4){0.f,0.f,0.f,0.f};
    const u16* Ap = A + (size_t)(row0+im)*lda + q*8;
    const u16* Wp = W + (size_t)(col0+im)*Kdim + q*8;
    for (int k0 = 0; k0 < Kdim; k0 += 32) {
        s16x8 af = *(const s16x8*)(Ap + k0);
        #pragma unroll
        for (int n=0;n<4;++n) {
            s16x8 bf = *(const s16x8*)(Wp + (size_t)n*16*Kdim + k0);
            acc[n] = __builtin_amdgcn_mfma_f32_16x16x32_bf16(af, bf, acc[n], 0, 0, 0);
        }
    }
    #pragma unroll
    for (int n=0;n<4;++n) {
        int col = col0 + n*16 + im;
        float bv = bias ? bias[col] : 0.f;
        #pragma unroll
        for (int r=0;r<4;++r) {
            int row = row0 + q*4 + r;
            float v = acc[n][r] + bv;
            if (ACT) v = silu_f(v);
            if (C)  C[(size_t)row*ldc + col] = v;
            if (Cb) Cb[(size_t)row*ldcb + col] = f2b(v);
            if (Cq) Cq[((size_t)row*FD + (col & 127))*4 + (col >> 7) + qoff] = f2b(v);
        }
    }
}

// ---------------- agg edge step ----------------
__device__ __forceinline__ void edge_step(
    const EdgeRec& er, ushort4 s4, ushort4 v4,
    const h16x2* wp,   // 30 pairs: [0..9]=row f, [10..19]=row 128+f, [20..29]=row 256+f
    float b0, float b1, float b2,
    float& acc_s, float& av0, float& av1, float& av2)
{
    union { h16x8 v; h16x2 p[4]; } e0, e1;
    union { h16x4 v; h16x2 p[2]; } e2;
    e0.v = er.es0; e1.v = er.es1; e2.v = er.es2;
    h16x2 ep[10] = {e0.p[0],e0.p[1],e0.p[2],e0.p[3],
                    e1.p[0],e1.p[1],e1.p[2],e1.p[3],
                    e2.p[0],e2.p[1]};
    float4 ed = er.ed;
    float d0=0.f, d1=0.f, d2=0.f;
    #pragma unroll
    for (int j=0;j<10;++j){
        d0 = FDOT2(ep[j], wp[j],    d0);
        d1 = FDOT2(ep[j], wp[10+j], d1);
        d2 = FDOT2(ep[j], wp[20+j], d2);
    }
    float g_sv = d0 + b0*ed.w;
    float g_ev = d1 + b1*ed.w;
    float g_ns = d2 + b2*ed.w;
    float fo_sv = g_sv * b2f(s4.x);
    float fo_ev = g_ev * b2f(s4.y);
    float fo_ns = g_ns * b2f(s4.z);
    acc_s += b2f(s4.w) * fo_ns;
    av0 += b2f(v4.x)*fo_sv + fo_ev*ed.x;
    av1 += b2f(v4.y)*fo_sv + fo_ev*ed.y;
    av2 += b2f(v4.z)*fo_sv + fo_ev*ed.z;
}

// ---------------- fused filter + gather aggregation ----------------
// 256 threads: f = tid&127, sub = tid>>7; node = blockIdx*2+sub (one node per slot).
// f16 filter weights (30 VGPRs/thread); waves_per_eu(3,4) => 128-reg budget, no spill.
__global__ __launch_bounds__(256) __attribute__((amdgpu_waves_per_eu(3,4)))
void agg_kernel(
    const float* __restrict__ s_prev_f, int s_ldaf,
    const float* __restrict__ v_prev_f, int v_nstrf,
    const ushort4* __restrict__ sq, const ushort4* __restrict__ vq,
    const EdgeRec* __restrict__ erec_csr,
    const int* __restrict__ sd_csr, const int* __restrict__ row_off,
    const _Float16* __restrict__ wf, const float* __restrict__ fb,
    float* __restrict__ s_mid, float* __restrict__ v_mid, u16* __restrict__ vmid_bf)
{
    const int f   = threadIdx.x & 127;
    const int sub = threadIdx.x >> 7;
    h16x2 wp[30];
    #pragma unroll
    for (int rsel=0; rsel<3; ++rsel){
        const h16x4* rp = (const h16x4*)(wf + (size_t)(rsel*FD + f)*KR);
        #pragma unroll
        for (int i=0;i<5;++i){
            union { h16x4 v; h16x2 p[2]; } t; t.v = rp[i];
            wp[rsel*10+2*i]   = t.p[0];
            wp[rsel*10+2*i+1] = t.p[1];
        }
    }
    const float b0 = fb[f], b1 = fb[FD+f], b2 = fb[2*FD+f];

    const int n = blockIdx.x*2 + sub;
    const int beg = row_off[n], end = row_off[n+1];
    float acc_s=0.f, av0=0.f, av1=0.f, av2=0.f;
    int idx = beg;
    int sd0 = (beg   < end) ? sd_csr[beg]   : 0;
    int sd1 = (beg+1 < end) ? sd_csr[beg+1] : 0;
    for (; idx + 2 <= end; idx += 2) {
        ushort4 sA = sq[(size_t)sd0*FD + f];
        ushort4 vA = vq[(size_t)sd0*FD + f];
        ushort4 sB = sq[(size_t)sd1*FD + f];
        ushort4 vB = vq[(size_t)sd1*FD + f];
        int nsd0 = (idx+2 < end) ? sd_csr[idx+2] : 0;
        int nsd1 = (idx+3 < end) ? sd_csr[idx+3] : 0;
        edge_step(erec_csr[idx],   sA, vA, wp, b0,b1,b2, acc_s, av0, av1, av2);
        edge_step(erec_csr[idx+1], sB, vB, wp, b0,b1,b2, acc_s, av0, av1, av2);
        sd0 = nsd0; sd1 = nsd1;
    }
    if (idx < end) {
        ushort4 sA = sq[(size_t)sd0*FD + f];
        ushort4 vA = vq[(size_t)sd0*FD + f];
        edge_step(erec_csr[idx], sA, vA, wp, b0,b1,b2, acc_s, av0, av1, av2);
    }
    s_mid[(size_t)n*FD+f] = s_prev_f[(size_t)n*s_ldaf+f] + acc_s;
    const float* vp = v_prev_f + (size_t)n*v_nstrf;
    float o0 = vp[f]+av0, o1 = vp[FD+f]+av1, o2 = vp[2*FD+f]+av2;
    size_t vo = (size_t)n*F3;
    v_mid[vo+f]=o0;        v_mid[vo+FD+f]=o1;        v_mid[vo+2*FD+f]=o2;
    vmid_bf[vo+f]=f2b(o0); vmid_bf[vo+FD+f]=f2b(o1); vmid_bf[vo+2*FD+f]=f2b(o2);
}

// ---------------- Vn, dot(Uv,Vv); m = [s_mid, Vn] (bf16) ----------------
__global__ __launch_bounds__(256) void vndot_kernel(
    const float* __restrict__ Uv, const float* __restrict__ Vv,
    const float* __restrict__ s_mid,
    u16* __restrict__ mbuf, float* __restrict__ dotb)
{
    int t = blockIdx.x * blockDim.x + threadIdx.x;   // NTOT*128
    int n = t >> 7, f = t & 127;
    size_t b0 = (size_t)n*3*FD + f;
    float u0 = Uv[b0], u1 = Uv[b0+FD], u2 = Uv[b0+2*FD];
    float w0 = Vv[b0], w1 = Vv[b0+FD], w2 = Vv[b0+2*FD];
    float vn  = sqrtf(w0*w0 + w1*w1 + w2*w2);
    dotb[t] = u0*w0 + u1*w1 + u2*w2;
    mbuf[(size_t)n*256 + f]      = f2b(s_mid[t]);
    mbuf[(size_t)n*256 + FD + f] = f2b(vn);
}

// ---------------- epilogue -> out slice + bf16/quad state for next layer ----------------
__global__ __launch_bounds__(256) void epi_kernel(
    const float* __restrict__ s_mid, const float* __restrict__ v_mid,
    const float* __restrict__ a, const float* __restrict__ dotb,
    const float* __restrict__ Uv, float* __restrict__ outp,
    u16* __restrict__ s_new_b, u16* __restrict__ sq, u16* __restrict__ vq)
{
    int t = blockIdx.x * blockDim.x + threadIdx.x;   // NTOT*128
    int n = t >> 7, f = t & 127;
    float a_ss = a[(size_t)n*F3 + f];
    float a_sv = a[(size_t)n*F3 + FD + f];
    float a_vv = a[(size_t)n*F3 + 2*FD + f];
    float sval = s_mid[t] + a_ss + a_sv*dotb[t];
    outp[(size_t)n*512 + f] = sval;
    s_new_b[t] = f2b(sval);
    sq[(size_t)t*4 + 3] = f2b(sval);
    #pragma unroll
    for (int c=0;c<3;++c) {
        size_t vi = ((size_t)n*3 + c)*FD + f;
        float vval = v_mid[vi] + a_vv*Uv[vi];
        outp[(size_t)n*512 + (1+c)*FD + f] = vval;
        vq[(size_t)t*4 + c] = f2b(vval);
    }
}

extern "C" void kernel_launch(void* const* d_in, const int* in_sizes, int n_in,
                              void* d_out, int out_size, void* d_ws, size_t ws_size,
                              hipStream_t stream)
{
    (void)in_sizes; (void)n_in; (void)out_size; (void)ws_size;
    const float* atom_xyz = (const float*)d_in[0];
    const float* cell     = (const float*)d_in[1];
    const int*   nodes    = (const int*)d_in[2];
    const int*   aedges   = (const int*)d_in[3];
    const float* edisp    = (const float*)d_in[4];
    const float* V_flat   = (const float*)d_in[5];
    const float* E_flat   = (const float*)d_in[6];
    const float* atom_emb = (const float*)d_in[7];
    const float* pot_W    = (const float*)d_in[8];
    const float* pot_b    = (const float*)d_in[9];
    const float* init_W1  = (const float*)d_in[10];
    const float* init_b1  = (const float*)d_in[11];
    const float* init_W2  = (const float*)d_in[12];
    const float* init_b2  = (const float*)d_in[13];
    const float* vec_w    = (const float*)d_in[14];
    const float* filt_W   = (const float*)d_in[15];
    const float* filt_b   = (const float*)d_in[16];
    const float* msg_W1   = (const float*)d_in[17];
    const float* msg_b1   = (const float*)d_in[18];
    const float* msg_W2   = (const float*)d_in[19];
    const float* msg_b2   = (const float*)d_in[20];
    const float* U_W      = (const float*)d_in[21];
    const float* V_W      = (const float*)d_in[22];
    const float* upd_W1   = (const float*)d_in[23];
    const float* upd_b1   = (const float*)d_in[24];
    const float* upd_W2   = (const float*)d_in[25];
    const float* upd_b2   = (const float*)d_in[26];

    float* out = (float*)d_out;
    char* base = (char*)d_ws;
    size_t o = 0;
    auto alloc = [&](size_t bytes)->char* { char* r = base + o; o += (bytes + 255) & ~(size_t)255; return r; };

    float* s0     = (float*)alloc((size_t)NTOT*FD*4);
    float* v0     = (float*)alloc((size_t)NTOT*F3*4);
    float* s_mid  = (float*)alloc((size_t)NTOT*FD*4);
    float* v_mid  = (float*)alloc((size_t)NTOT*F3*4);
    float* Uv     = (float*)alloc((size_t)NTOT*F3*4);
    float* Vv     = (float*)alloc((size_t)NTOT*F3*4);   // reused as 'a'
    float* dotb   = (float*)alloc((size_t)NTOT*FD*4);
    EdgeRec* erec     = (EdgeRec*)alloc((size_t)ETOT*sizeof(EdgeRec));
    EdgeRec* erec_csr = (EdgeRec*)alloc((size_t)ETOT*sizeof(EdgeRec));
    u16* h_bf     = (u16*)alloc((size_t)NTOT*256*2);    // reused as mbuf
    u16* s_bf     = (u16*)alloc((size_t)NTOT*FD*2);
    u16* sq       = (u16*)alloc((size_t)NTOT*FD*4*2);   // quads {so0,so1,so2,s}
    u16* vq       = (u16*)alloc((size_t)NTOT*FD*4*2);   // quads {v0,v1,v2,-}
    u16* hid_bf   = (u16*)alloc((size_t)NTOT*FD*2);
    u16* vmid_bf  = (u16*)alloc((size_t)NTOT*F3*2);
    u16* wts      = (u16*)alloc((size_t)589824*2);
    _Float16* wf16 = (_Float16*)alloc((size_t)3*F3*KR*2);
    int* sendb    = (int*)alloc((size_t)ETOT*4);
    int* recvb    = (int*)alloc((size_t)ETOT*4);
    int* sd_csr   = (int*)alloc((size_t)ETOT*4);
    int* row_off  = (int*)alloc((size_t)(NTOT+1)*4);
    int* counts   = (int*)alloc((size_t)NTOT*4);
    int* cursor   = (int*)alloc((size_t)NTOT*4);

    hipMemsetAsync(counts, 0, NTOT*sizeof(int), stream);
    hipMemsetAsync(cursor, 0, NTOT*sizeof(int), stream);

    edge_kernel<<<ETOT/256, 256, 0, stream>>>(atom_xyz, cell, aedges, edisp,
        sendb, recvb, erec, counts);
    scan_kernel<<<1, 1024, 0, stream>>>(counts, row_off);
    fill_kernel<<<ETOT/256, 256, 0, stream>>>(recvb, sendb, erec,
        row_off, cursor, sd_csr, erec_csr);
    wconv_kernel<<<(589824+255)/256, 256, 0, stream>>>(
        init_W1, init_W2, msg_W1, msg_W2, U_W, V_W, upd_W1, upd_W2, wts);
    wfilt_kernel<<<(3*F3*KR+255)/256, 256, 0, stream>>>(filt_W, wf16);

    const u16* w_init1 = wts + 0;
    const u16* w_init2 = wts + 32768;
    const u16* w_msg1  = wts + 49152;    // 3 x 16384
    const u16* w_msg2  = wts + 98304;    // 3 x 49152
    const u16* w_U     = wts + 245760;   // 3 x 16384
    const u16* w_V     = wts + 294912;   // 3 x 16384
    const u16* w_upd1  = wts + 344064;   // 3 x 32768
    const u16* w_upd2  = wts + 442368;   // 3 x 49152

    hbuild_kernel<<<NTOT*256/256, 256, 0, stream>>>(nodes, atom_emb, V_flat, pot_W, pot_b, h_bf);
    bgemm_kernel<1><<<dim3(FD/64, NTOT/64), 256, 0, stream>>>(
        h_bf, 256, w_init1, 256, init_b1, (float*)nullptr, 0, hid_bf, FD, (u16*)nullptr, 0);
    bgemm_kernel<0><<<dim3(FD/64, NTOT/64), 256, 0, stream>>>(
        hid_bf, FD, w_init2, FD, init_b2, s0, FD, s_bf, FD, sq, 3);
    v0_kernel<<<NTOT*F3/256, 256, 0, stream>>>(E_flat, vec_w, v0, vq);

    const float* s_prev_f = s0;  int s_ldaf  = FD;
    const float* v_prev_f = v0;  int v_nstrf = 3*FD;
    for (int l = 0; l < 3; ++l) {
        bgemm_kernel<1><<<dim3(FD/64, NTOT/64), 256, 0, stream>>>(
            s_bf, FD, w_msg1 + (size_t)l*16384, FD, msg_b1 + (size_t)l*FD,
            (float*)nullptr, 0, hid_bf, FD, (u16*)nullptr, 0);
        bgemm_kernel<0><<<dim3(F3/64, NTOT/64), 256, 0, stream>>>(
            hid_bf, FD, w_msg2 + (size_t)l*49152, FD, msg_b2 + (size_t)l*F3,
            (float*)nullptr, 0, (u16*)nullptr, 0, sq, 0);
        agg_kernel<<<NTOT/2, 256, 0, stream>>>(s_prev_f, s_ldaf, v_prev_f, v_nstrf,
            (const ushort4*)sq, (const ushort4*)vq, erec_csr, sd_csr, row_off,
            wf16 + (size_t)l*F3*KR, filt_b + (size_t)l*F3, s_mid, v_mid, vmid_bf);
        bgemm_kernel<0><<<dim3(FD/64, 3*NTOT/64), 256, 0, stream>>>(
            vmid_bf, FD, w_U + (size_t)l*16384, FD, (const float*)nullptr,
            Uv, FD, (u16*)nullptr, 0, (u16*)nullptr, 0);
        bgemm_kernel<0><<<dim3(FD/64, 3*NTOT/64), 256, 0, stream>>>(
            vmid_bf, FD, w_V + (size_t)l*16384, FD, (const float*)nullptr,
            Vv, FD, (u16*)nullptr, 0, (u16*)nullptr, 0);
        vndot_kernel<<<NTOT*FD/256, 256, 0, stream>>>(Uv, Vv, s_mid, h_bf, dotb);
        bgemm_kernel<1><<<dim3(FD/64, NTOT/64), 256, 0, stream>>>(
            h_bf, 256, w_upd1 + (size_t)l*32768, 256, upd_b1 + (size_t)l*FD,
            (float*)nullptr, 0, hid_bf, FD, (u16*)nullptr, 0);
        bgemm_kernel<0><<<dim3(F3/64, NTOT/64), 256, 0, stream>>>(
            hid_bf, FD, w_upd2 + (size_t)l*49152, FD, upd_b2 + (size_t)l*F3,
            Vv, F3, (u16*)nullptr, 0, (u16*)nullptr, 0);   // Vv reused as 'a'
        float* outp = out + (size_t)l*NTOT*512;
        epi_kernel<<<NTOT*FD/256, 256, 0, stream>>>(s_mid, v_mid, Vv, dotb, Uv, outp,
            s_bf, sq, vq);
        s_prev_f = outp;        s_ldaf  = 512;
        v_prev_f = outp + FD;   v_nstrf = 512;
    }
}